// Round 2
// baseline (406.004 us; speedup 1.0000x reference)
//
#include <hip/hip_runtime.h>
#include <hip/hip_bf16.h>

#define HEADS 8
#define DK 64
#define DV 64
#define DM 512
#define ROUNDS 2
#define SEQ 4096
#define BUCKET 64
#define NCHUNK 64
#define BATCH 4

typedef __hip_bfloat16 bf16;

__device__ __forceinline__ float u2f(unsigned short u) {
  union { unsigned int i; float f; } c;
  c.i = ((unsigned int)u) << 16;
  return c.f;  // exact bf16 -> fp32
}
__device__ __forceinline__ unsigned short f2bu(float x) {
  bf16 h = __float2bfloat16(x);  // RNE, same as verified version
  return *reinterpret_cast<unsigned short*>(&h);
}

// ---------------------------------------------------------------------------
// Kernel 1: hash. h[r][b][s] = argmax([q@R, -q@R]) + 1, in 1..64.
// Register-tiled fp64 GEMM (2q x 4m per thread = 8 independent dfma chains).
// ---------------------------------------------------------------------------
__global__ __launch_bounds__(256) void hash_kernel(const float* __restrict__ q,
                                                   const float* __restrict__ R,
                                                   int* __restrict__ h_out) {
  int blk = blockIdx.x;
  int stile = blk & 63;
  int b = (blk >> 6) & (BATCH - 1);
  int r = blk >> 8;
  int s0 = stile << 6;
  int rb = r * BATCH + b;

  __shared__ double Qd[64 * 65];  // 33280 B
  __shared__ double Rd[64 * 32];  // 16384 B

  int tid = threadIdx.x;
  int qg = tid >> 3;  // 0..31
  int cg = tid & 7;   // 0..7
  int q0 = qg << 1;
  int m0 = cg << 2;

  int qrow = tid & 63;
  int qd0 = (tid >> 6) << 4;
  const float* qbase = q + ((size_t)b * SEQ + s0 + qrow) * DM;
  const float* rbase = R + (size_t)r * DM * 32;

  float4 qreg[4];
  float rr[8];
#pragma unroll
  for (int c = 0; c < 4; ++c)
    qreg[c] = *reinterpret_cast<const float4*>(qbase + qd0 + c * 4);
#pragma unroll
  for (int j = 0; j < 8; ++j) rr[j] = rbase[j * 256 + tid];

  double acc[2][4];
#pragma unroll
  for (int qq = 0; qq < 2; ++qq)
#pragma unroll
    for (int mm = 0; mm < 4; ++mm) acc[qq][mm] = 0.0;

  for (int t = 0; t < 8; ++t) {
#pragma unroll
    for (int c = 0; c < 4; ++c) {
      double* dst = &Qd[qrow * 65 + qd0 + c * 4];
      dst[0] = (double)qreg[c].x;
      dst[1] = (double)qreg[c].y;
      dst[2] = (double)qreg[c].z;
      dst[3] = (double)qreg[c].w;
    }
#pragma unroll
    for (int j = 0; j < 8; ++j) Rd[j * 256 + tid] = (double)rr[j];
    __syncthreads();

    if (t < 7) {
      int dt = t + 1;
#pragma unroll
      for (int c = 0; c < 4; ++c)
        qreg[c] = *reinterpret_cast<const float4*>(qbase + dt * 64 + qd0 + c * 4);
#pragma unroll
      for (int j = 0; j < 8; ++j) rr[j] = rbase[dt * 2048 + j * 256 + tid];
    }

#pragma unroll 4
    for (int d = 0; d < 64; ++d) {
      double qa = Qd[q0 * 65 + d];
      double qb = Qd[(q0 + 1) * 65 + d];
      double rv0 = Rd[d * 32 + m0 + 0];
      double rv1 = Rd[d * 32 + m0 + 1];
      double rv2 = Rd[d * 32 + m0 + 2];
      double rv3 = Rd[d * 32 + m0 + 3];
      acc[0][0] = fma(qa, rv0, acc[0][0]);
      acc[0][1] = fma(qa, rv1, acc[0][1]);
      acc[0][2] = fma(qa, rv2, acc[0][2]);
      acc[0][3] = fma(qa, rv3, acc[0][3]);
      acc[1][0] = fma(qb, rv0, acc[1][0]);
      acc[1][1] = fma(qb, rv1, acc[1][1]);
      acc[1][2] = fma(qb, rv2, acc[1][2]);
      acc[1][3] = fma(qb, rv3, acc[1][3]);
    }
    __syncthreads();
  }

  double bv[2];
  int bi[2];
#pragma unroll
  for (int qq = 0; qq < 2; ++qq) {
    double v = acc[qq][0];
    int i = m0;
#pragma unroll
    for (int mm = 1; mm < 4; ++mm)
      if (acc[qq][mm] > v) { v = acc[qq][mm]; i = m0 + mm; }
#pragma unroll
    for (int mm = 0; mm < 4; ++mm) {
      double nv = -acc[qq][mm];
      if (nv > v) { v = nv; i = 32 + m0 + mm; }
    }
    bv[qq] = v;
    bi[qq] = i;
  }
#pragma unroll
  for (int off = 1; off < 8; off <<= 1) {
#pragma unroll
    for (int qq = 0; qq < 2; ++qq) {
      double ov = __shfl_xor(bv[qq], off);
      int oi = __shfl_xor(bi[qq], off);
      if (ov > bv[qq] || (ov == bv[qq] && oi < bi[qq])) { bv[qq] = ov; bi[qq] = oi; }
    }
  }
  if (cg == 0) {
#pragma unroll
    for (int qq = 0; qq < 2; ++qq)
      h_out[(size_t)rb * SEQ + s0 + q0 + qq] = bi[qq] + 1;
  }
}

// ---------------------------------------------------------------------------
// Kernel 2: stable counting sort by bucket per (r,b).
// ---------------------------------------------------------------------------
__global__ __launch_bounds__(256) void sort_kernel(const int* __restrict__ h,
                                                   int* __restrict__ sorted_idx) {
  int rb = blockIdx.x;
  const int* hp = h + (size_t)rb * SEQ;
  __shared__ unsigned char hs[SEQ];
  __shared__ int tile_cnt[64][64];
  __shared__ int tile_base[64][64];
  __shared__ int bucket_base[64];
  __shared__ int bucket_tot[64];
  for (int i = threadIdx.x; i < 64 * 64; i += 256) ((int*)tile_cnt)[i] = 0;
  __syncthreads();
  for (int s = threadIdx.x; s < SEQ; s += 256) {
    int hv = hp[s] - 1;
    hs[s] = (unsigned char)hv;
    atomicAdd(&tile_cnt[s >> 6][hv], 1);
  }
  __syncthreads();
  if (threadIdx.x < 64) {
    int bkt = threadIdx.x;
    int run = 0;
    for (int t = 0; t < 64; ++t) { tile_base[t][bkt] = run; run += tile_cnt[t][bkt]; }
    bucket_tot[bkt] = run;
  }
  __syncthreads();
  if (threadIdx.x == 0) {
    int run = 0;
    for (int bkt = 0; bkt < 64; ++bkt) { bucket_base[bkt] = run; run += bucket_tot[bkt]; }
  }
  __syncthreads();
  for (int s = threadIdx.x; s < SEQ; s += 256) {
    int t = s >> 6;
    int bkt = hs[s];
    int rank = 0;
    for (int j = t << 6; j < s; ++j) rank += (hs[j] == bkt) ? 1 : 0;
    int pos = bucket_base[bkt] + tile_base[t][bkt] + rank;
    sorted_idx[(size_t)rb * SEQ + pos] = s;
  }
}

// ---------------------------------------------------------------------------
// Kernel 3: chunked LSH attention, conflict-free LDS layout.
//   Kt [d][j] stride 132 fp32 (K transposed)  -> b128 reads, segments 8 banks
//   Qt [d][i] stride  68 fp32 (Q transposed)  -> scalar reads, 16 banks
//   S  [q][k] stride 129 fp32 (reuses Kt)     -> stride ≡ 1 (mod 32)
//   V  [l][dv] stride 68 bf16 (reuses Qt)     -> aligned ushort4 reads
// Thread q-rows are {qt, qt+16, qt+32, qt+48} so S accesses hit 2 lanes/bank.
// Softmax: row = tid&63 (64 distinct rows per wave), segs combined via LDS.
// All FMA accumulation orders identical to the verified version.
// ---------------------------------------------------------------------------
__global__ __launch_bounds__(256) void attn_kernel(
    const float* __restrict__ q, const float* __restrict__ k,
    const float* __restrict__ v, const int* __restrict__ h,
    const int* __restrict__ sidx, float* __restrict__ out, int r,
    int accumulate) {
  int x = blockIdx.x;
  int hd = x & 7;
  int n = (x >> 3) & 63;
  int b = x >> 9;
  int rb = r * BATCH + b;

  __shared__ float KS[64 * 132];  // 33792 B: Kt fp32 -> S fp32 (64 x 129)
  __shared__ float QV[64 * 68];   // 17408 B: Qt fp32 -> V bf16 (128 x 68)
  __shared__ int orig_w[128];
  __shared__ int hw[128];
  __shared__ float redmax[4][64];
  __shared__ float redsum[4][64];
  bf16* Vv = reinterpret_cast<bf16*>(QV);
  float* S = KS;  // stride 129

  int tid = threadIdx.x;
  if (tid < 128) {
    int j = tid;
    int sp = (j < 64) ? ((((n + 63) & 63) << 6) + j) : ((n << 6) + (j - 64));
    int orig = sidx[(size_t)rb * SEQ + sp];
    orig_w[j] = orig;
    hw[j] = h[(size_t)rb * SEQ + orig];
  }
  __syncthreads();

  // Stage K transposed [d][j] and Q transposed [d][i].
  for (int idx = tid; idx < 128 * 16; idx += 256) {
    int j = idx >> 4, dq = idx & 15;
    float4 kk = *reinterpret_cast<const float4*>(
        k + ((size_t)b * SEQ + orig_w[j]) * DM + hd * 64 + dq * 4);
    KS[(dq * 4 + 0) * 132 + j] = kk.x;
    KS[(dq * 4 + 1) * 132 + j] = kk.y;
    KS[(dq * 4 + 2) * 132 + j] = kk.z;
    KS[(dq * 4 + 3) * 132 + j] = kk.w;
  }
  for (int idx = tid; idx < 64 * 16; idx += 256) {
    int i = idx >> 4, dq = idx & 15;
    float4 qq4 = *reinterpret_cast<const float4*>(
        q + ((size_t)b * SEQ + orig_w[64 + i]) * DM + hd * 64 + dq * 4);
    QV[(dq * 4 + 0) * 68 + i] = qq4.x;
    QV[(dq * 4 + 1) * 68 + i] = qq4.y;
    QV[(dq * 4 + 2) * 68 + i] = qq4.z;
    QV[(dq * 4 + 3) * 68 + i] = qq4.w;
  }
  __syncthreads();

  // QK^T: thread tile = q-rows {qt+16*qq} x 8 consecutive k.
  int qt = tid & 15, kt = tid >> 4;
  int k0 = kt * 8;
  float acc[4][8];
#pragma unroll
  for (int qq = 0; qq < 4; ++qq)
#pragma unroll
    for (int jj = 0; jj < 8; ++jj) acc[qq][jj] = 0.f;

#pragma unroll 2
  for (int d = 0; d < 64; ++d) {
    const float4* kp = reinterpret_cast<const float4*>(&KS[d * 132 + k0]);
    float4 ka = kp[0], kb = kp[1];
    float kr[8] = {ka.x, ka.y, ka.z, ka.w, kb.x, kb.y, kb.z, kb.w};
    float qv[4];
#pragma unroll
    for (int qq = 0; qq < 4; ++qq) qv[qq] = QV[d * 68 + qt + 16 * qq];
#pragma unroll
    for (int qq = 0; qq < 4; ++qq)
#pragma unroll
      for (int jj = 0; jj < 8; ++jj)
        acc[qq][jj] = fmaf(qv[qq], kr[jj], acc[qq][jj]);
  }
  // Scale + masks in registers.
#pragma unroll
  for (int qq = 0; qq < 4; ++qq) {
    int i = qt + 16 * qq;
    int hq = hw[64 + i];
#pragma unroll
    for (int jj = 0; jj < 8; ++jj) {
      int j = k0 + jj;
      float lg = acc[qq][jj] * 0.125f;
      if (hw[j] != hq) lg = -1e15f;   // bucket mask
      if (j == 64 + i) lg -= 1e5f;    // self mask
      acc[qq][jj] = lg;
    }
  }
  __syncthreads();  // all Kt/Qt reads complete

  // Write S (stride 129, 2 lanes/bank); stage V bf16 (stride 68, ushort4).
#pragma unroll
  for (int qq = 0; qq < 4; ++qq) {
    int i = qt + 16 * qq;
#pragma unroll
    for (int jj = 0; jj < 8; ++jj) S[i * 129 + k0 + jj] = acc[qq][jj];
  }
  for (int idx = tid; idx < 128 * 16; idx += 256) {
    int j = idx >> 4, dq = idx & 15;
    float4 vv4 = *reinterpret_cast<const float4*>(
        v + ((size_t)b * SEQ + orig_w[j]) * DM + hd * 64 + dq * 4);
    ushort4 us;
    us.x = f2bu(vv4.x);
    us.y = f2bu(vv4.y);
    us.z = f2bu(vv4.z);
    us.w = f2bu(vv4.w);
    *reinterpret_cast<ushort4*>(&Vv[j * 68 + dq * 4]) = us;
  }
  __syncthreads();

  // Softmax: row = tid&63 (64 distinct rows/wave -> 2 lanes/bank), seg = tid>>6.
  {
    int row = tid & 63, seg = tid >> 6;
    float* Srow = S + row * 129 + seg * 32;
    float mx = -INFINITY;
#pragma unroll 8
    for (int t = 0; t < 32; ++t) mx = fmaxf(mx, Srow[t]);
    redmax[seg][row] = mx;
    __syncthreads();
    mx = fmaxf(fmaxf(redmax[0][row], redmax[1][row]),
               fmaxf(redmax[2][row], redmax[3][row]));
    float sm = 0.f;
#pragma unroll 8
    for (int t = 0; t < 32; ++t) {
      float ev = __expf(Srow[t] - mx);
      Srow[t] = ev;
      sm += ev;
    }
    redsum[seg][row] = sm;
    __syncthreads();
    sm = (redsum[0][row] + redsum[1][row]) + (redsum[2][row] + redsum[3][row]);
    float inv = 1.0f / sm;
#pragma unroll 8
    for (int t = 0; t < 32; ++t) Srow[t] *= inv;
  }
  __syncthreads();

  // P @ V: q-rows {qt+16*qq} x 4 consecutive dv.
  int dv0 = (tid >> 4) * 4;
  float o[4][4];
#pragma unroll
  for (int qq = 0; qq < 4; ++qq)
#pragma unroll
    for (int dd = 0; dd < 4; ++dd) o[qq][dd] = 0.f;

#pragma unroll 2
  for (int l = 0; l < 128; ++l) {
    ushort4 uv = *reinterpret_cast<const ushort4*>(&Vv[l * 68 + dv0]);
    float vv[4] = {u2f(uv.x), u2f(uv.y), u2f(uv.z), u2f(uv.w)};
#pragma unroll
    for (int qq = 0; qq < 4; ++qq) {
      float pv = S[(qt + 16 * qq) * 129 + l];
#pragma unroll
      for (int dd = 0; dd < 4; ++dd) o[qq][dd] = fmaf(pv, vv[dd], o[qq][dd]);
    }
  }

  // FP32 output through the inverse permutation (16B per row segment).
#pragma unroll
  for (int qq = 0; qq < 4; ++qq) {
    int i = qt + 16 * qq;
    float* dst = out + ((size_t)b * SEQ + orig_w[64 + i]) * DM + hd * 64 + dv0;
    if (accumulate) {
      float4 cur = *reinterpret_cast<float4*>(dst);
      cur.x += o[qq][0]; cur.y += o[qq][1]; cur.z += o[qq][2]; cur.w += o[qq][3];
      *reinterpret_cast<float4*>(dst) = cur;
    } else {
      float4 st = {o[qq][0], o[qq][1], o[qq][2], o[qq][3]};
      *reinterpret_cast<float4*>(dst) = st;
    }
  }
}

extern "C" void kernel_launch(void* const* d_in, const int* in_sizes, int n_in,
                              void* d_out, int out_size, void* d_ws,
                              size_t ws_size, hipStream_t stream) {
  (void)out_size; (void)ws_size;
  const int R_ELEMS = ROUNDS * DM * 32;
  const float *q, *k, *v, *R;
  if (n_in >= 4 && in_sizes[0] == R_ELEMS) {  // defensive; dict order is live
    R = (const float*)d_in[0];
    k = (const float*)d_in[1];
    q = (const float*)d_in[2];
    v = (const float*)d_in[3];
  } else {
    q = (const float*)d_in[0];
    k = (const float*)d_in[1];
    v = (const float*)d_in[2];
    R = (const float*)d_in[3];
  }
  float* out = (float*)d_out;  // REFERENCE OUTPUT IS FP32
  char* ws = (char*)d_ws;
  int* h = (int*)ws;                                   // 128 KB
  int* sidx = (int*)(ws + ROUNDS * BATCH * SEQ * 4);   // 128 KB

  hash_kernel<<<ROUNDS * BATCH * (SEQ / 64), 256, 0, stream>>>(q, R, h);
  sort_kernel<<<ROUNDS * BATCH, 256, 0, stream>>>(h, sidx);
  attn_kernel<<<BATCH * NCHUNK * HEADS, 256, 0, stream>>>(q, k, v, h, sidx, out, 0, 0);
  attn_kernel<<<BATCH * NCHUNK * HEADS, 256, 0, stream>>>(q, k, v, h, sidx, out, 1, 1);
}

// Round 3
// 364.375 us; speedup vs baseline: 1.1142x; 1.1142x over previous
//
#include <hip/hip_runtime.h>
#include <hip/hip_bf16.h>
#include <hip/hip_fp16.h>

#define HEADS 8
#define DK 64
#define DV 64
#define DM 512
#define ROUNDS 2
#define SEQ 4096
#define BUCKET 64
#define NCHUNK 64
#define BATCH 4

typedef __hip_bfloat16 bf16;

__device__ __forceinline__ float u2f(unsigned short u) {
  union { unsigned int i; float f; } c;
  c.i = ((unsigned int)u) << 16;
  return c.f;  // exact bf16 -> fp32
}
__device__ __forceinline__ unsigned short f2bu(float x) {
  bf16 h = __float2bfloat16(x);  // RNE, same as verified version
  return *reinterpret_cast<unsigned short*>(&h);
}

// ---------------------------------------------------------------------------
// Kernel 1: hash. h[r][b][s] = argmax([q@R, -q@R]) + 1, in 1..64.
// Register-tiled fp64 GEMM (2q x 4m per thread = 8 independent dfma chains).
// ---------------------------------------------------------------------------
__global__ __launch_bounds__(256) void hash_kernel(const float* __restrict__ q,
                                                   const float* __restrict__ R,
                                                   int* __restrict__ h_out) {
  int blk = blockIdx.x;
  int stile = blk & 63;
  int b = (blk >> 6) & (BATCH - 1);
  int r = blk >> 8;
  int s0 = stile << 6;
  int rb = r * BATCH + b;

  __shared__ double Qd[64 * 65];  // 33280 B
  __shared__ double Rd[64 * 32];  // 16384 B

  int tid = threadIdx.x;
  int qg = tid >> 3;  // 0..31
  int cg = tid & 7;   // 0..7
  int q0 = qg << 1;
  int m0 = cg << 2;

  int qrow = tid & 63;
  int qd0 = (tid >> 6) << 4;
  const float* qbase = q + ((size_t)b * SEQ + s0 + qrow) * DM;
  const float* rbase = R + (size_t)r * DM * 32;

  float4 qreg[4];
  float rr[8];
#pragma unroll
  for (int c = 0; c < 4; ++c)
    qreg[c] = *reinterpret_cast<const float4*>(qbase + qd0 + c * 4);
#pragma unroll
  for (int j = 0; j < 8; ++j) rr[j] = rbase[j * 256 + tid];

  double acc[2][4];
#pragma unroll
  for (int qq = 0; qq < 2; ++qq)
#pragma unroll
    for (int mm = 0; mm < 4; ++mm) acc[qq][mm] = 0.0;

  for (int t = 0; t < 8; ++t) {
#pragma unroll
    for (int c = 0; c < 4; ++c) {
      double* dst = &Qd[qrow * 65 + qd0 + c * 4];
      dst[0] = (double)qreg[c].x;
      dst[1] = (double)qreg[c].y;
      dst[2] = (double)qreg[c].z;
      dst[3] = (double)qreg[c].w;
    }
#pragma unroll
    for (int j = 0; j < 8; ++j) Rd[j * 256 + tid] = (double)rr[j];
    __syncthreads();

    if (t < 7) {
      int dt = t + 1;
#pragma unroll
      for (int c = 0; c < 4; ++c)
        qreg[c] = *reinterpret_cast<const float4*>(qbase + dt * 64 + qd0 + c * 4);
#pragma unroll
      for (int j = 0; j < 8; ++j) rr[j] = rbase[dt * 2048 + j * 256 + tid];
    }

#pragma unroll 4
    for (int d = 0; d < 64; ++d) {
      double qa = Qd[q0 * 65 + d];
      double qb = Qd[(q0 + 1) * 65 + d];
      double rv0 = Rd[d * 32 + m0 + 0];
      double rv1 = Rd[d * 32 + m0 + 1];
      double rv2 = Rd[d * 32 + m0 + 2];
      double rv3 = Rd[d * 32 + m0 + 3];
      acc[0][0] = fma(qa, rv0, acc[0][0]);
      acc[0][1] = fma(qa, rv1, acc[0][1]);
      acc[0][2] = fma(qa, rv2, acc[0][2]);
      acc[0][3] = fma(qa, rv3, acc[0][3]);
      acc[1][0] = fma(qb, rv0, acc[1][0]);
      acc[1][1] = fma(qb, rv1, acc[1][1]);
      acc[1][2] = fma(qb, rv2, acc[1][2]);
      acc[1][3] = fma(qb, rv3, acc[1][3]);
    }
    __syncthreads();
  }

  double bv[2];
  int bi[2];
#pragma unroll
  for (int qq = 0; qq < 2; ++qq) {
    double v = acc[qq][0];
    int i = m0;
#pragma unroll
    for (int mm = 1; mm < 4; ++mm)
      if (acc[qq][mm] > v) { v = acc[qq][mm]; i = m0 + mm; }
#pragma unroll
    for (int mm = 0; mm < 4; ++mm) {
      double nv = -acc[qq][mm];
      if (nv > v) { v = nv; i = 32 + m0 + mm; }
    }
    bv[qq] = v;
    bi[qq] = i;
  }
#pragma unroll
  for (int off = 1; off < 8; off <<= 1) {
#pragma unroll
    for (int qq = 0; qq < 2; ++qq) {
      double ov = __shfl_xor(bv[qq], off);
      int oi = __shfl_xor(bi[qq], off);
      if (ov > bv[qq] || (ov == bv[qq] && oi < bi[qq])) { bv[qq] = ov; bi[qq] = oi; }
    }
  }
  if (cg == 0) {
#pragma unroll
    for (int qq = 0; qq < 2; ++qq)
      h_out[(size_t)rb * SEQ + s0 + q0 + qq] = bi[qq] + 1;
  }
}

// ---------------------------------------------------------------------------
// Kernel 2: stable counting sort by bucket per (r,b).
// ---------------------------------------------------------------------------
__global__ __launch_bounds__(256) void sort_kernel(const int* __restrict__ h,
                                                   int* __restrict__ sorted_idx) {
  int rb = blockIdx.x;
  const int* hp = h + (size_t)rb * SEQ;
  __shared__ unsigned char hs[SEQ];
  __shared__ int tile_cnt[64][64];
  __shared__ int tile_base[64][64];
  __shared__ int bucket_base[64];
  __shared__ int bucket_tot[64];
  for (int i = threadIdx.x; i < 64 * 64; i += 256) ((int*)tile_cnt)[i] = 0;
  __syncthreads();
  for (int s = threadIdx.x; s < SEQ; s += 256) {
    int hv = hp[s] - 1;
    hs[s] = (unsigned char)hv;
    atomicAdd(&tile_cnt[s >> 6][hv], 1);
  }
  __syncthreads();
  if (threadIdx.x < 64) {
    int bkt = threadIdx.x;
    int run = 0;
    for (int t = 0; t < 64; ++t) { tile_base[t][bkt] = run; run += tile_cnt[t][bkt]; }
    bucket_tot[bkt] = run;
  }
  __syncthreads();
  if (threadIdx.x == 0) {
    int run = 0;
    for (int bkt = 0; bkt < 64; ++bkt) { bucket_base[bkt] = run; run += bucket_tot[bkt]; }
  }
  __syncthreads();
  for (int s = threadIdx.x; s < SEQ; s += 256) {
    int t = s >> 6;
    int bkt = hs[s];
    int rank = 0;
    for (int j = t << 6; j < s; ++j) rank += (hs[j] == bkt) ? 1 : 0;
    int pos = bucket_base[bkt] + tile_base[t][bkt] + rank;
    sorted_idx[(size_t)rb * SEQ + pos] = s;
  }
}

// ---------------------------------------------------------------------------
// Kernel 3: chunked LSH attention, register-resident S (flash-style).
// Per wave: 16 q-rows; per lane: 1 q-row (qrow) x 32 k-cols (kt*32..+31).
// K staged in d-halves [32][140] fp32 (+4-word pad per kt group: the 8
// ds_read_b128/d hit disjoint bank quads). Q [32][68] fp32. After QK^T the
// softmax runs entirely in registers (2 shfl_xor for row reduce; reduction
// order bit-identical to the verified LDS version). P stored fp16 (rel err
// 5e-4 -> out err ~0.002), V bf16 as verified. Peak LDS ~35.4 KB -> 4
// blocks/CU (was 3). Global loads T14-split: half2 under QKT1, V under QKT2.
// ---------------------------------------------------------------------------
__global__ __launch_bounds__(256) void attn_kernel(
    const float* __restrict__ q, const float* __restrict__ k,
    const float* __restrict__ v, const int* __restrict__ h,
    const int* __restrict__ sidx, float* __restrict__ out, int r,
    int accumulate) {
  int x = blockIdx.x;
  int hd = x & 7;
  int n = (x >> 3) & 63;
  int b = x >> 9;
  int rb = r * BATCH + b;

  // Phase A: K fp32 [32][140] at [0,17920), Q fp32 [32][68] at [17920,26624)
  // Phase B: P fp16 [64][132] at [0,16896), V bf16 [128][68] at [16896,34304)
  __shared__ __align__(16) unsigned char smem[34304];
  __shared__ int orig_w[128];
  __shared__ int hw[128];
  float* KH = reinterpret_cast<float*>(smem);
  float* QH = reinterpret_cast<float*>(smem + 17920);
  __half* Pl = reinterpret_cast<__half*>(smem);
  __half2* Ph2 = reinterpret_cast<__half2*>(smem);
  bf16* Vv = reinterpret_cast<bf16*>(smem + 16896);

  int tid = threadIdx.x;
  if (tid < 128) {
    int j = tid;
    int sp = (j < 64) ? ((((n + 63) & 63) << 6) + j) : ((n << 6) + (j - 64));
    int orig = sidx[(size_t)rb * SEQ + sp];
    orig_w[j] = orig;
    hw[j] = h[(size_t)rb * SEQ + orig];
  }
  __syncthreads();

  const size_t gbase = (size_t)b * SEQ * DM + hd * 64;

  // lane identity for compute: 1 q-row x 32 k-cols
  int qrow = ((tid >> 6) << 4) | (tid & 15);  // wave*16 + (lane&15)
  int ktl = (tid >> 4) & 3;                   // k-group within wave
  int ktOff = ktl * 36;                       // padded LDS col base
  int cbase = ktl * 32;                       // logical k-col base

  float4 kreg[4], qreg[2], vreg[8];

  // ---- load half 0 (d in [0,32)) ----
#pragma unroll
  for (int t = 0; t < 4; ++t) {
    int idx = tid + t * 256;
    int j = idx >> 3, f4 = idx & 7;
    kreg[t] = *reinterpret_cast<const float4*>(
        k + gbase + (size_t)orig_w[j] * DM + f4 * 4);
  }
#pragma unroll
  for (int t = 0; t < 2; ++t) {
    int idx = tid + t * 256;
    int i = idx >> 3, f4 = idx & 7;
    qreg[t] = *reinterpret_cast<const float4*>(
        q + gbase + (size_t)orig_w[64 + i] * DM + f4 * 4);
  }
  // write half 0 to LDS
#pragma unroll
  for (int t = 0; t < 4; ++t) {
    int idx = tid + t * 256;
    int j = idx >> 3, f4 = idx & 7;
    int col = j + ((j >> 5) << 2);
    float* dst = &KH[(f4 * 4) * 140 + col];
    dst[0 * 140] = kreg[t].x; dst[1 * 140] = kreg[t].y;
    dst[2 * 140] = kreg[t].z; dst[3 * 140] = kreg[t].w;
  }
#pragma unroll
  for (int t = 0; t < 2; ++t) {
    int idx = tid + t * 256;
    int i = idx >> 3, f4 = idx & 7;
    float* dst = &QH[(f4 * 4) * 68 + i];
    dst[0 * 68] = qreg[t].x; dst[1 * 68] = qreg[t].y;
    dst[2 * 68] = qreg[t].z; dst[3 * 68] = qreg[t].w;
  }
  __syncthreads();

  // issue half-1 global loads (in flight during QKT half 0)
#pragma unroll
  for (int t = 0; t < 4; ++t) {
    int idx = tid + t * 256;
    int j = idx >> 3, f4 = idx & 7;
    kreg[t] = *reinterpret_cast<const float4*>(
        k + gbase + (size_t)orig_w[j] * DM + 32 + f4 * 4);
  }
#pragma unroll
  for (int t = 0; t < 2; ++t) {
    int idx = tid + t * 256;
    int i = idx >> 3, f4 = idx & 7;
    qreg[t] = *reinterpret_cast<const float4*>(
        q + gbase + (size_t)orig_w[64 + i] * DM + 32 + f4 * 4);
  }

  float s[32];
#pragma unroll
  for (int j = 0; j < 32; ++j) s[j] = 0.f;

  // QKT over d = 0..31 (ascending: same accumulation order as verified)
#pragma unroll 2
  for (int d = 0; d < 32; ++d) {
    float qv = QH[d * 68 + qrow];
    const float* kd = &KH[d * 140 + ktOff];
#pragma unroll
    for (int t4 = 0; t4 < 8; ++t4) {
      float4 kk = *reinterpret_cast<const float4*>(kd + t4 * 4);
      s[t4 * 4 + 0] = fmaf(qv, kk.x, s[t4 * 4 + 0]);
      s[t4 * 4 + 1] = fmaf(qv, kk.y, s[t4 * 4 + 1]);
      s[t4 * 4 + 2] = fmaf(qv, kk.z, s[t4 * 4 + 2]);
      s[t4 * 4 + 3] = fmaf(qv, kk.w, s[t4 * 4 + 3]);
    }
  }
  __syncthreads();  // half-0 reads done

  // write half 1 to LDS
#pragma unroll
  for (int t = 0; t < 4; ++t) {
    int idx = tid + t * 256;
    int j = idx >> 3, f4 = idx & 7;
    int col = j + ((j >> 5) << 2);
    float* dst = &KH[(f4 * 4) * 140 + col];
    dst[0 * 140] = kreg[t].x; dst[1 * 140] = kreg[t].y;
    dst[2 * 140] = kreg[t].z; dst[3 * 140] = kreg[t].w;
  }
#pragma unroll
  for (int t = 0; t < 2; ++t) {
    int idx = tid + t * 256;
    int i = idx >> 3, f4 = idx & 7;
    float* dst = &QH[(f4 * 4) * 68 + i];
    dst[0 * 68] = qreg[t].x; dst[1 * 68] = qreg[t].y;
    dst[2 * 68] = qreg[t].z; dst[3 * 68] = qreg[t].w;
  }
  __syncthreads();

  // issue V global loads (in flight during QKT half 1)
#pragma unroll
  for (int t = 0; t < 8; ++t) {
    int idx = tid + t * 256;
    int j = idx >> 4, dq = idx & 15;
    vreg[t] = *reinterpret_cast<const float4*>(
        v + gbase + (size_t)orig_w[j] * DM + dq * 4);
  }

  // QKT over d = 32..63
#pragma unroll 2
  for (int d = 0; d < 32; ++d) {
    float qv = QH[d * 68 + qrow];
    const float* kd = &KH[d * 140 + ktOff];
#pragma unroll
    for (int t4 = 0; t4 < 8; ++t4) {
      float4 kk = *reinterpret_cast<const float4*>(kd + t4 * 4);
      s[t4 * 4 + 0] = fmaf(qv, kk.x, s[t4 * 4 + 0]);
      s[t4 * 4 + 1] = fmaf(qv, kk.y, s[t4 * 4 + 1]);
      s[t4 * 4 + 2] = fmaf(qv, kk.z, s[t4 * 4 + 2]);
      s[t4 * 4 + 3] = fmaf(qv, kk.w, s[t4 * 4 + 3]);
    }
  }

  // Scale + masks (identical logic to verified version)
  {
    int hq = hw[64 + qrow];
#pragma unroll
    for (int j = 0; j < 32; ++j) {
      int c = cbase + j;
      float lg = s[j] * 0.125f;
      if (hw[c] != hq) lg = -1e15f;       // bucket mask
      if (c == 64 + qrow) lg -= 1e5f;     // self mask
      s[j] = lg;
    }
  }

  // Softmax fully in registers. Reduction order matches verified version:
  // per-segment ascending partials, then (s0+s1)+(s2+s3) (commutative-safe).
  {
    float mx = -INFINITY;
#pragma unroll
    for (int j = 0; j < 32; ++j) mx = fmaxf(mx, s[j]);
    mx = fmaxf(mx, __shfl_xor(mx, 16));
    mx = fmaxf(mx, __shfl_xor(mx, 32));
    float sm = 0.f;
#pragma unroll
    for (int j = 0; j < 32; ++j) {
      float ev = __expf(s[j] - mx);
      s[j] = ev;
      sm += ev;
    }
    float sm2 = sm + __shfl_xor(sm, 16);
    float smT = sm2 + __shfl_xor(sm2, 32);
    float inv = 1.0f / smT;
#pragma unroll
    for (int j = 0; j < 32; ++j) s[j] *= inv;
  }
  __syncthreads();  // all K/Q LDS reads complete; safe to overlay P/V

  // Write P fp16 (half2) and V bf16 (ushort4)
  {
    int pbase = qrow * 66 + ktl * 16;  // half2 index, stride 132 halfwords
#pragma unroll
    for (int t = 0; t < 16; ++t)
      Ph2[pbase + t] = __floats2half2_rn(s[2 * t], s[2 * t + 1]);
  }
#pragma unroll
  for (int t = 0; t < 8; ++t) {
    int idx = tid + t * 256;
    int j = idx >> 4, dq = idx & 15;
    ushort4 us;
    us.x = f2bu(vreg[t].x);
    us.y = f2bu(vreg[t].y);
    us.z = f2bu(vreg[t].z);
    us.w = f2bu(vreg[t].w);
    *reinterpret_cast<ushort4*>(&Vv[j * 68 + dq * 4]) = us;
  }
  __syncthreads();

  // P @ V: thread computes 4q x 4dv (q-rows {qt2+16qq}), ascending l.
  int qt2 = tid & 15, dv0 = (tid >> 4) * 4;
  float o[4][4];
#pragma unroll
  for (int qq = 0; qq < 4; ++qq)
#pragma unroll
    for (int dd = 0; dd < 4; ++dd) o[qq][dd] = 0.f;

#pragma unroll 2
  for (int l = 0; l < 128; ++l) {
    ushort4 uv = *reinterpret_cast<const ushort4*>(&Vv[l * 68 + dv0]);
    float vv[4] = {u2f(uv.x), u2f(uv.y), u2f(uv.z), u2f(uv.w)};
#pragma unroll
    for (int qq = 0; qq < 4; ++qq) {
      float pv = __half2float(Pl[(qt2 + 16 * qq) * 132 + l]);
#pragma unroll
      for (int dd = 0; dd < 4; ++dd) o[qq][dd] = fmaf(pv, vv[dd], o[qq][dd]);
    }
  }

  // FP32 output through the inverse permutation (16B per row segment).
#pragma unroll
  for (int qq = 0; qq < 4; ++qq) {
    int i = qt2 + 16 * qq;
    float* dst = out + gbase + (size_t)orig_w[64 + i] * DM + dv0;
    if (accumulate) {
      float4 cur = *reinterpret_cast<float4*>(dst);
      cur.x += o[qq][0]; cur.y += o[qq][1]; cur.z += o[qq][2]; cur.w += o[qq][3];
      *reinterpret_cast<float4*>(dst) = cur;
    } else {
      float4 st = {o[qq][0], o[qq][1], o[qq][2], o[qq][3]};
      *reinterpret_cast<float4*>(dst) = st;
    }
  }
}

extern "C" void kernel_launch(void* const* d_in, const int* in_sizes, int n_in,
                              void* d_out, int out_size, void* d_ws,
                              size_t ws_size, hipStream_t stream) {
  (void)out_size; (void)ws_size;
  const int R_ELEMS = ROUNDS * DM * 32;
  const float *q, *k, *v, *R;
  if (n_in >= 4 && in_sizes[0] == R_ELEMS) {  // defensive; dict order is live
    R = (const float*)d_in[0];
    k = (const float*)d_in[1];
    q = (const float*)d_in[2];
    v = (const float*)d_in[3];
  } else {
    q = (const float*)d_in[0];
    k = (const float*)d_in[1];
    v = (const float*)d_in[2];
    R = (const float*)d_in[3];
  }
  float* out = (float*)d_out;  // REFERENCE OUTPUT IS FP32
  char* ws = (char*)d_ws;
  int* h = (int*)ws;                                   // 128 KB
  int* sidx = (int*)(ws + ROUNDS * BATCH * SEQ * 4);   // 128 KB

  hash_kernel<<<ROUNDS * BATCH * (SEQ / 64), 256, 0, stream>>>(q, R, h);
  sort_kernel<<<ROUNDS * BATCH, 256, 0, stream>>>(h, sidx);
  attn_kernel<<<BATCH * NCHUNK * HEADS, 256, 0, stream>>>(q, k, v, h, sidx, out, 0, 0);
  attn_kernel<<<BATCH * NCHUNK * HEADS, 256, 0, stream>>>(q, k, v, h, sidx, out, 1, 1);
}

// Round 4
// 336.845 us; speedup vs baseline: 1.2053x; 1.0817x over previous
//
#include <hip/hip_runtime.h>
#include <hip/hip_bf16.h>
#include <hip/hip_fp16.h>

#define HEADS 8
#define DK 64
#define DV 64
#define DM 512
#define ROUNDS 2
#define SEQ 4096
#define BUCKET 64
#define NCHUNK 64
#define BATCH 4

typedef __hip_bfloat16 bf16;

__device__ __forceinline__ float u2f(unsigned short u) {
  union { unsigned int i; float f; } c;
  c.i = ((unsigned int)u) << 16;
  return c.f;  // exact bf16 -> fp32
}
__device__ __forceinline__ unsigned short f2bu(float x) {
  bf16 h = __float2bfloat16(x);  // RNE, same as verified version
  return *reinterpret_cast<unsigned short*>(&h);
}

// ---------------------------------------------------------------------------
// Kernel 1: hash. h[r][b][s] = argmax([q@R, -q@R]) + 1, in 1..64.
// fp64 accumulation (bit-identical to verified version: staged values are the
// original fp32 bits, converted to double in registers -- exact; same d order).
// LDS now fp32: Qf transposed [d][row] (float2 reads), Rf [d][m] (float4
// reads). 24.5 KB -> 6 blocks/CU (was 3 at fp64 staging).
// ---------------------------------------------------------------------------
__global__ __launch_bounds__(256) void hash_kernel(const float* __restrict__ q,
                                                   const float* __restrict__ R,
                                                   int* __restrict__ h_out) {
  int blk = blockIdx.x;
  int stile = blk & 63;
  int b = (blk >> 6) & (BATCH - 1);
  int r = blk >> 8;
  int s0 = stile << 6;
  int rb = r * BATCH + b;

  __shared__ float Qf[64 * 66];  // 16896 B, [d][row], stride 66 (8B-aligned rows)
  __shared__ float Rf[64 * 32];  // 8192 B, [d][m]

  int tid = threadIdx.x;
  int qg = tid >> 3;  // 0..31
  int cg = tid & 7;   // 0..7
  int q0 = qg << 1;
  int m0 = cg << 2;

  int qrow = tid & 63;
  int qd0 = (tid >> 6) << 4;
  const float* qbase = q + ((size_t)b * SEQ + s0 + qrow) * DM;
  const float* rbase = R + (size_t)r * DM * 32;

  float4 qreg[4];
  float rr[8];
#pragma unroll
  for (int c = 0; c < 4; ++c)
    qreg[c] = *reinterpret_cast<const float4*>(qbase + qd0 + c * 4);
#pragma unroll
  for (int j = 0; j < 8; ++j) rr[j] = rbase[j * 256 + tid];

  double acc[2][4];
#pragma unroll
  for (int qq = 0; qq < 2; ++qq)
#pragma unroll
    for (int mm = 0; mm < 4; ++mm) acc[qq][mm] = 0.0;

  for (int t = 0; t < 8; ++t) {
    // staged registers -> LDS (fp32, Q transposed)
#pragma unroll
    for (int c = 0; c < 4; ++c) {
      int d = qd0 + c * 4;
      Qf[(d + 0) * 66 + qrow] = qreg[c].x;
      Qf[(d + 1) * 66 + qrow] = qreg[c].y;
      Qf[(d + 2) * 66 + qrow] = qreg[c].z;
      Qf[(d + 3) * 66 + qrow] = qreg[c].w;
    }
#pragma unroll
    for (int j = 0; j < 8; ++j) Rf[j * 256 + tid] = rr[j];
    __syncthreads();

    // issue next tile's global loads; latency hides under compute
    if (t < 7) {
      int dt = t + 1;
#pragma unroll
      for (int c = 0; c < 4; ++c)
        qreg[c] = *reinterpret_cast<const float4*>(qbase + dt * 64 + qd0 + c * 4);
#pragma unroll
      for (int j = 0; j < 8; ++j) rr[j] = rbase[dt * 2048 + j * 256 + tid];
    }

    // per d: 1 b64 (Q pair) + 1 b128 (R quad) + 6 cvt + 8 dfma
#pragma unroll 4
    for (int d = 0; d < 64; ++d) {
      float2 qf = *reinterpret_cast<const float2*>(&Qf[d * 66 + q0]);
      float4 rf = *reinterpret_cast<const float4*>(&Rf[d * 32 + m0]);
      double qa = (double)qf.x;
      double qb = (double)qf.y;
      double rv0 = (double)rf.x;
      double rv1 = (double)rf.y;
      double rv2 = (double)rf.z;
      double rv3 = (double)rf.w;
      acc[0][0] = fma(qa, rv0, acc[0][0]);
      acc[0][1] = fma(qa, rv1, acc[0][1]);
      acc[0][2] = fma(qa, rv2, acc[0][2]);
      acc[0][3] = fma(qa, rv3, acc[0][3]);
      acc[1][0] = fma(qb, rv0, acc[1][0]);
      acc[1][1] = fma(qb, rv1, acc[1][1]);
      acc[1][2] = fma(qb, rv2, acc[1][2]);
      acc[1][3] = fma(qb, rv3, acc[1][3]);
    }
    __syncthreads();
  }

  // argmax over 64 candidates [rot, -rot], first-max (lowest index) wins.
  double bv[2];
  int bi[2];
#pragma unroll
  for (int qq = 0; qq < 2; ++qq) {
    double v = acc[qq][0];
    int i = m0;
#pragma unroll
    for (int mm = 1; mm < 4; ++mm)
      if (acc[qq][mm] > v) { v = acc[qq][mm]; i = m0 + mm; }
#pragma unroll
    for (int mm = 0; mm < 4; ++mm) {
      double nv = -acc[qq][mm];
      if (nv > v) { v = nv; i = 32 + m0 + mm; }
    }
    bv[qq] = v;
    bi[qq] = i;
  }
#pragma unroll
  for (int off = 1; off < 8; off <<= 1) {
#pragma unroll
    for (int qq = 0; qq < 2; ++qq) {
      double ov = __shfl_xor(bv[qq], off);
      int oi = __shfl_xor(bi[qq], off);
      if (ov > bv[qq] || (ov == bv[qq] && oi < bi[qq])) { bv[qq] = ov; bi[qq] = oi; }
    }
  }
  if (cg == 0) {
#pragma unroll
    for (int qq = 0; qq < 2; ++qq)
      h_out[(size_t)rb * SEQ + s0 + q0 + qq] = bi[qq] + 1;
  }
}

// ---------------------------------------------------------------------------
// Kernel 2: stable counting sort by bucket per (r,b).
// One wave per 64-element tile. Per-lane match-mask via 6 ballots:
// rank = popc(mask & lanes_below) -- replaces the divergent 63-iteration
// serial scan. Histogram free from the same mask (rank-0 lane writes count).
// Stability: rank follows lane order = s order. Bit-identical output.
// ---------------------------------------------------------------------------
__global__ __launch_bounds__(256) void sort_kernel(const int* __restrict__ h,
                                                   int* __restrict__ sorted_idx) {
  int rb = blockIdx.x;
  const int* hp = h + (size_t)rb * SEQ;
  __shared__ unsigned char hs[SEQ];
  __shared__ unsigned char rs[SEQ];
  __shared__ int tile_cnt[64][64];
  __shared__ int tile_base[64][64];
  __shared__ int bucket_base[64];
  __shared__ int bucket_tot[64];
  int tid = threadIdx.x;
  int wave = tid >> 6, lane = tid & 63;
  for (int i = tid; i < 64 * 64; i += 256) ((int*)tile_cnt)[i] = 0;
  __syncthreads();
  for (int t = wave; t < 64; t += 4) {
    int s = (t << 6) + lane;
    int hv = hp[s] - 1;
    unsigned long long mm = ~0ull;
#pragma unroll
    for (int bit = 0; bit < 6; ++bit) {
      unsigned long long bb = __ballot((hv >> bit) & 1);
      mm &= ((hv >> bit) & 1) ? bb : ~bb;
    }
    int rank = __popcll(mm & ((1ull << lane) - 1ull));
    hs[s] = (unsigned char)hv;
    rs[s] = (unsigned char)rank;
    if (rank == 0) tile_cnt[t][hv] = __popcll(mm);
  }
  __syncthreads();
  if (tid < 64) {
    int bkt = tid;
    int run = 0;
    for (int t = 0; t < 64; ++t) { tile_base[t][bkt] = run; run += tile_cnt[t][bkt]; }
    bucket_tot[bkt] = run;
  }
  __syncthreads();
  if (tid == 0) {
    int run = 0;
    for (int bkt = 0; bkt < 64; ++bkt) { bucket_base[bkt] = run; run += bucket_tot[bkt]; }
  }
  __syncthreads();
  for (int t = wave; t < 64; t += 4) {
    int s = (t << 6) + lane;
    int hv = hs[s];
    int pos = bucket_base[hv] + tile_base[t][hv] + rs[s];
    sorted_idx[(size_t)rb * SEQ + pos] = s;
  }
}

// ---------------------------------------------------------------------------
// Kernel 3: chunked LSH attention, register-resident S (flash-style).
// (unchanged from verified round-2 version)
// ---------------------------------------------------------------------------
__global__ __launch_bounds__(256) void attn_kernel(
    const float* __restrict__ q, const float* __restrict__ k,
    const float* __restrict__ v, const int* __restrict__ h,
    const int* __restrict__ sidx, float* __restrict__ out, int r,
    int accumulate) {
  int x = blockIdx.x;
  int hd = x & 7;
  int n = (x >> 3) & 63;
  int b = x >> 9;
  int rb = r * BATCH + b;

  // Phase A: K fp32 [32][140] at [0,17920), Q fp32 [32][68] at [17920,26624)
  // Phase B: P fp16 [64][132] at [0,16896), V bf16 [128][68] at [16896,34304)
  __shared__ __align__(16) unsigned char smem[34304];
  __shared__ int orig_w[128];
  __shared__ int hw[128];
  float* KH = reinterpret_cast<float*>(smem);
  float* QH = reinterpret_cast<float*>(smem + 17920);
  __half* Pl = reinterpret_cast<__half*>(smem);
  __half2* Ph2 = reinterpret_cast<__half2*>(smem);
  bf16* Vv = reinterpret_cast<bf16*>(smem + 16896);

  int tid = threadIdx.x;
  if (tid < 128) {
    int j = tid;
    int sp = (j < 64) ? ((((n + 63) & 63) << 6) + j) : ((n << 6) + (j - 64));
    int orig = sidx[(size_t)rb * SEQ + sp];
    orig_w[j] = orig;
    hw[j] = h[(size_t)rb * SEQ + orig];
  }
  __syncthreads();

  const size_t gbase = (size_t)b * SEQ * DM + hd * 64;

  // lane identity for compute: 1 q-row x 32 k-cols
  int qrow = ((tid >> 6) << 4) | (tid & 15);  // wave*16 + (lane&15)
  int ktl = (tid >> 4) & 3;                   // k-group within wave
  int ktOff = ktl * 36;                       // padded LDS col base
  int cbase = ktl * 32;                       // logical k-col base

  float4 kreg[4], qreg[2], vreg[8];

  // ---- load half 0 (d in [0,32)) ----
#pragma unroll
  for (int t = 0; t < 4; ++t) {
    int idx = tid + t * 256;
    int j = idx >> 3, f4 = idx & 7;
    kreg[t] = *reinterpret_cast<const float4*>(
        k + gbase + (size_t)orig_w[j] * DM + f4 * 4);
  }
#pragma unroll
  for (int t = 0; t < 2; ++t) {
    int idx = tid + t * 256;
    int i = idx >> 3, f4 = idx & 7;
    qreg[t] = *reinterpret_cast<const float4*>(
        q + gbase + (size_t)orig_w[64 + i] * DM + f4 * 4);
  }
  // write half 0 to LDS
#pragma unroll
  for (int t = 0; t < 4; ++t) {
    int idx = tid + t * 256;
    int j = idx >> 3, f4 = idx & 7;
    int col = j + ((j >> 5) << 2);
    float* dst = &KH[(f4 * 4) * 140 + col];
    dst[0 * 140] = kreg[t].x; dst[1 * 140] = kreg[t].y;
    dst[2 * 140] = kreg[t].z; dst[3 * 140] = kreg[t].w;
  }
#pragma unroll
  for (int t = 0; t < 2; ++t) {
    int idx = tid + t * 256;
    int i = idx >> 3, f4 = idx & 7;
    float* dst = &QH[(f4 * 4) * 68 + i];
    dst[0 * 68] = qreg[t].x; dst[1 * 68] = qreg[t].y;
    dst[2 * 68] = qreg[t].z; dst[3 * 68] = qreg[t].w;
  }
  __syncthreads();

  // issue half-1 global loads (in flight during QKT half 0)
#pragma unroll
  for (int t = 0; t < 4; ++t) {
    int idx = tid + t * 256;
    int j = idx >> 3, f4 = idx & 7;
    kreg[t] = *reinterpret_cast<const float4*>(
        k + gbase + (size_t)orig_w[j] * DM + 32 + f4 * 4);
  }
#pragma unroll
  for (int t = 0; t < 2; ++t) {
    int idx = tid + t * 256;
    int i = idx >> 3, f4 = idx & 7;
    qreg[t] = *reinterpret_cast<const float4*>(
        q + gbase + (size_t)orig_w[64 + i] * DM + 32 + f4 * 4);
  }

  float s[32];
#pragma unroll
  for (int j = 0; j < 32; ++j) s[j] = 0.f;

  // QKT over d = 0..31 (ascending: same accumulation order as verified)
#pragma unroll 2
  for (int d = 0; d < 32; ++d) {
    float qv = QH[d * 68 + qrow];
    const float* kd = &KH[d * 140 + ktOff];
#pragma unroll
    for (int t4 = 0; t4 < 8; ++t4) {
      float4 kk = *reinterpret_cast<const float4*>(kd + t4 * 4);
      s[t4 * 4 + 0] = fmaf(qv, kk.x, s[t4 * 4 + 0]);
      s[t4 * 4 + 1] = fmaf(qv, kk.y, s[t4 * 4 + 1]);
      s[t4 * 4 + 2] = fmaf(qv, kk.z, s[t4 * 4 + 2]);
      s[t4 * 4 + 3] = fmaf(qv, kk.w, s[t4 * 4 + 3]);
    }
  }
  __syncthreads();  // half-0 reads done

  // write half 1 to LDS
#pragma unroll
  for (int t = 0; t < 4; ++t) {
    int idx = tid + t * 256;
    int j = idx >> 3, f4 = idx & 7;
    int col = j + ((j >> 5) << 2);
    float* dst = &KH[(f4 * 4) * 140 + col];
    dst[0 * 140] = kreg[t].x; dst[1 * 140] = kreg[t].y;
    dst[2 * 140] = kreg[t].z; dst[3 * 140] = kreg[t].w;
  }
#pragma unroll
  for (int t = 0; t < 2; ++t) {
    int idx = tid + t * 256;
    int i = idx >> 3, f4 = idx & 7;
    float* dst = &QH[(f4 * 4) * 68 + i];
    dst[0 * 68] = qreg[t].x; dst[1 * 68] = qreg[t].y;
    dst[2 * 68] = qreg[t].z; dst[3 * 68] = qreg[t].w;
  }
  __syncthreads();

  // issue V global loads (in flight during QKT half 1)
#pragma unroll
  for (int t = 0; t < 8; ++t) {
    int idx = tid + t * 256;
    int j = idx >> 4, dq = idx & 15;
    vreg[t] = *reinterpret_cast<const float4*>(
        v + gbase + (size_t)orig_w[j] * DM + dq * 4);
  }

  // QKT over d = 32..63
#pragma unroll 2
  for (int d = 0; d < 32; ++d) {
    float qv = QH[d * 68 + qrow];
    const float* kd = &KH[d * 140 + ktOff];
#pragma unroll
    for (int t4 = 0; t4 < 8; ++t4) {
      float4 kk = *reinterpret_cast<const float4*>(kd + t4 * 4);
      s[t4 * 4 + 0] = fmaf(qv, kk.x, s[t4 * 4 + 0]);
      s[t4 * 4 + 1] = fmaf(qv, kk.y, s[t4 * 4 + 1]);
      s[t4 * 4 + 2] = fmaf(qv, kk.z, s[t4 * 4 + 2]);
      s[t4 * 4 + 3] = fmaf(qv, kk.w, s[t4 * 4 + 3]);
    }
  }

  // Scale + masks (identical logic to verified version)
  {
    int hq = hw[64 + qrow];
#pragma unroll
    for (int j = 0; j < 32; ++j) {
      int c = cbase + j;
      float lg = s[j] * 0.125f;
      if (hw[c] != hq) lg = -1e15f;       // bucket mask
      if (c == 64 + qrow) lg -= 1e5f;     // self mask
      s[j] = lg;
    }
  }

  // Softmax fully in registers. Reduction order matches verified version:
  // per-segment ascending partials, then (s0+s1)+(s2+s3) (commutative-safe).
  {
    float mx = -INFINITY;
#pragma unroll
    for (int j = 0; j < 32; ++j) mx = fmaxf(mx, s[j]);
    mx = fmaxf(mx, __shfl_xor(mx, 16));
    mx = fmaxf(mx, __shfl_xor(mx, 32));
    float sm = 0.f;
#pragma unroll
    for (int j = 0; j < 32; ++j) {
      float ev = __expf(s[j] - mx);
      s[j] = ev;
      sm += ev;
    }
    float sm2 = sm + __shfl_xor(sm, 16);
    float smT = sm2 + __shfl_xor(sm2, 32);
    float inv = 1.0f / smT;
#pragma unroll
    for (int j = 0; j < 32; ++j) s[j] *= inv;
  }
  __syncthreads();  // all K/Q LDS reads complete; safe to overlay P/V

  // Write P fp16 (half2) and V bf16 (ushort4)
  {
    int pbase = qrow * 66 + ktl * 16;  // half2 index, stride 132 halfwords
#pragma unroll
    for (int t = 0; t < 16; ++t)
      Ph2[pbase + t] = __floats2half2_rn(s[2 * t], s[2 * t + 1]);
  }
#pragma unroll
  for (int t = 0; t < 8; ++t) {
    int idx = tid + t * 256;
    int j = idx >> 4, dq = idx & 15;
    ushort4 us;
    us.x = f2bu(vreg[t].x);
    us.y = f2bu(vreg[t].y);
    us.z = f2bu(vreg[t].z);
    us.w = f2bu(vreg[t].w);
    *reinterpret_cast<ushort4*>(&Vv[j * 68 + dq * 4]) = us;
  }
  __syncthreads();

  // P @ V: thread computes 4q x 4dv (q-rows {qt2+16qq}), ascending l.
  int qt2 = tid & 15, dv0 = (tid >> 4) * 4;
  float o[4][4];
#pragma unroll
  for (int qq = 0; qq < 4; ++qq)
#pragma unroll
    for (int dd = 0; dd < 4; ++dd) o[qq][dd] = 0.f;

#pragma unroll 2
  for (int l = 0; l < 128; ++l) {
    ushort4 uv = *reinterpret_cast<const ushort4*>(&Vv[l * 68 + dv0]);
    float vv[4] = {u2f(uv.x), u2f(uv.y), u2f(uv.z), u2f(uv.w)};
#pragma unroll
    for (int qq = 0; qq < 4; ++qq) {
      float pv = __half2float(Pl[(qt2 + 16 * qq) * 132 + l]);
#pragma unroll
      for (int dd = 0; dd < 4; ++dd) o[qq][dd] = fmaf(pv, vv[dd], o[qq][dd]);
    }
  }

  // FP32 output through the inverse permutation (16B per row segment).
#pragma unroll
  for (int qq = 0; qq < 4; ++qq) {
    int i = qt2 + 16 * qq;
    float* dst = out + gbase + (size_t)orig_w[64 + i] * DM + dv0;
    if (accumulate) {
      float4 cur = *reinterpret_cast<float4*>(dst);
      cur.x += o[qq][0]; cur.y += o[qq][1]; cur.z += o[qq][2]; cur.w += o[qq][3];
      *reinterpret_cast<float4*>(dst) = cur;
    } else {
      float4 st = {o[qq][0], o[qq][1], o[qq][2], o[qq][3]};
      *reinterpret_cast<float4*>(dst) = st;
    }
  }
}

extern "C" void kernel_launch(void* const* d_in, const int* in_sizes, int n_in,
                              void* d_out, int out_size, void* d_ws,
                              size_t ws_size, hipStream_t stream) {
  (void)out_size; (void)ws_size;
  const int R_ELEMS = ROUNDS * DM * 32;
  const float *q, *k, *v, *R;
  if (n_in >= 4 && in_sizes[0] == R_ELEMS) {  // defensive; dict order is live
    R = (const float*)d_in[0];
    k = (const float*)d_in[1];
    q = (const float*)d_in[2];
    v = (const float*)d_in[3];
  } else {
    q = (const float*)d_in[0];
    k = (const float*)d_in[1];
    v = (const float*)d_in[2];
    R = (const float*)d_in[3];
  }
  float* out = (float*)d_out;  // REFERENCE OUTPUT IS FP32
  char* ws = (char*)d_ws;
  int* h = (int*)ws;                                   // 128 KB
  int* sidx = (int*)(ws + ROUNDS * BATCH * SEQ * 4);   // 128 KB

  hash_kernel<<<ROUNDS * BATCH * (SEQ / 64), 256, 0, stream>>>(q, R, h);
  sort_kernel<<<ROUNDS * BATCH, 256, 0, stream>>>(h, sidx);
  attn_kernel<<<BATCH * NCHUNK * HEADS, 256, 0, stream>>>(q, k, v, h, sidx, out, 0, 0);
  attn_kernel<<<BATCH * NCHUNK * HEADS, 256, 0, stream>>>(q, k, v, h, sidx, out, 1, 1);
}

// Round 5
// 234.441 us; speedup vs baseline: 1.7318x; 1.4368x over previous
//
#include <hip/hip_runtime.h>
#include <hip/hip_bf16.h>
#include <hip/hip_fp16.h>

#define HEADS 8
#define DK 64
#define DV 64
#define DM 512
#define ROUNDS 2
#define SEQ 4096
#define BUCKET 64
#define NCHUNK 64
#define BATCH 4

typedef _Float16 f16;
typedef f16 f16x4 __attribute__((ext_vector_type(4)));
typedef f16 f16x8 __attribute__((ext_vector_type(8)));
typedef float f32x4 __attribute__((ext_vector_type(4)));

#define MFMA16(a, b, c) __builtin_amdgcn_mfma_f32_16x16x32_f16((a), (b), (c), 0, 0, 0)

// ---------------------------------------------------------------------------
// Kernel 1: hash. h[r][b][s] = argmax([q@R, -q@R]) + 1, in 1..64.
// fp64 accumulation (bit-identical results: staged fp32 bits, exact cvt to
// double in registers, ascending-d order). UNCHANGED from verified round-3.
// ---------------------------------------------------------------------------
__global__ __launch_bounds__(256) void hash_kernel(const float* __restrict__ q,
                                                   const float* __restrict__ R,
                                                   int* __restrict__ h_out) {
  int blk = blockIdx.x;
  int stile = blk & 63;
  int b = (blk >> 6) & (BATCH - 1);
  int r = blk >> 8;
  int s0 = stile << 6;
  int rb = r * BATCH + b;

  __shared__ float Qf[64 * 66];  // 16896 B, [d][row]
  __shared__ float Rf[64 * 32];  // 8192 B, [d][m]

  int tid = threadIdx.x;
  int qg = tid >> 3;  // 0..31
  int cg = tid & 7;   // 0..7
  int q0 = qg << 1;
  int m0 = cg << 2;

  int qrow = tid & 63;
  int qd0 = (tid >> 6) << 4;
  const float* qbase = q + ((size_t)b * SEQ + s0 + qrow) * DM;
  const float* rbase = R + (size_t)r * DM * 32;

  float4 qreg[4];
  float rr[8];
#pragma unroll
  for (int c = 0; c < 4; ++c)
    qreg[c] = *reinterpret_cast<const float4*>(qbase + qd0 + c * 4);
#pragma unroll
  for (int j = 0; j < 8; ++j) rr[j] = rbase[j * 256 + tid];

  double acc[2][4];
#pragma unroll
  for (int qq = 0; qq < 2; ++qq)
#pragma unroll
    for (int mm = 0; mm < 4; ++mm) acc[qq][mm] = 0.0;

  for (int t = 0; t < 8; ++t) {
#pragma unroll
    for (int c = 0; c < 4; ++c) {
      int d = qd0 + c * 4;
      Qf[(d + 0) * 66 + qrow] = qreg[c].x;
      Qf[(d + 1) * 66 + qrow] = qreg[c].y;
      Qf[(d + 2) * 66 + qrow] = qreg[c].z;
      Qf[(d + 3) * 66 + qrow] = qreg[c].w;
    }
#pragma unroll
    for (int j = 0; j < 8; ++j) Rf[j * 256 + tid] = rr[j];
    __syncthreads();

    if (t < 7) {
      int dt = t + 1;
#pragma unroll
      for (int c = 0; c < 4; ++c)
        qreg[c] = *reinterpret_cast<const float4*>(qbase + dt * 64 + qd0 + c * 4);
#pragma unroll
      for (int j = 0; j < 8; ++j) rr[j] = rbase[dt * 2048 + j * 256 + tid];
    }

#pragma unroll 4
    for (int d = 0; d < 64; ++d) {
      float2 qf = *reinterpret_cast<const float2*>(&Qf[d * 66 + q0]);
      float4 rf = *reinterpret_cast<const float4*>(&Rf[d * 32 + m0]);
      double qa = (double)qf.x;
      double qb = (double)qf.y;
      double rv0 = (double)rf.x;
      double rv1 = (double)rf.y;
      double rv2 = (double)rf.z;
      double rv3 = (double)rf.w;
      acc[0][0] = fma(qa, rv0, acc[0][0]);
      acc[0][1] = fma(qa, rv1, acc[0][1]);
      acc[0][2] = fma(qa, rv2, acc[0][2]);
      acc[0][3] = fma(qa, rv3, acc[0][3]);
      acc[1][0] = fma(qb, rv0, acc[1][0]);
      acc[1][1] = fma(qb, rv1, acc[1][1]);
      acc[1][2] = fma(qb, rv2, acc[1][2]);
      acc[1][3] = fma(qb, rv3, acc[1][3]);
    }
    __syncthreads();
  }

  double bv[2];
  int bi[2];
#pragma unroll
  for (int qq = 0; qq < 2; ++qq) {
    double v = acc[qq][0];
    int i = m0;
#pragma unroll
    for (int mm = 1; mm < 4; ++mm)
      if (acc[qq][mm] > v) { v = acc[qq][mm]; i = m0 + mm; }
#pragma unroll
    for (int mm = 0; mm < 4; ++mm) {
      double nv = -acc[qq][mm];
      if (nv > v) { v = nv; i = 32 + m0 + mm; }
    }
    bv[qq] = v;
    bi[qq] = i;
  }
#pragma unroll
  for (int off = 1; off < 8; off <<= 1) {
#pragma unroll
    for (int qq = 0; qq < 2; ++qq) {
      double ov = __shfl_xor(bv[qq], off);
      int oi = __shfl_xor(bi[qq], off);
      if (ov > bv[qq] || (ov == bv[qq] && oi < bi[qq])) { bv[qq] = ov; bi[qq] = oi; }
    }
  }
  if (cg == 0) {
#pragma unroll
    for (int qq = 0; qq < 2; ++qq)
      h_out[(size_t)rb * SEQ + s0 + q0 + qq] = bi[qq] + 1;
  }
}

// ---------------------------------------------------------------------------
// Kernel 2: stable counting sort (ballot match-mask). UNCHANGED from round-3.
// ---------------------------------------------------------------------------
__global__ __launch_bounds__(256) void sort_kernel(const int* __restrict__ h,
                                                   int* __restrict__ sorted_idx) {
  int rb = blockIdx.x;
  const int* hp = h + (size_t)rb * SEQ;
  __shared__ unsigned char hs[SEQ];
  __shared__ unsigned char rs[SEQ];
  __shared__ int tile_cnt[64][64];
  __shared__ int tile_base[64][64];
  __shared__ int bucket_base[64];
  __shared__ int bucket_tot[64];
  int tid = threadIdx.x;
  int wave = tid >> 6, lane = tid & 63;
  for (int i = tid; i < 64 * 64; i += 256) ((int*)tile_cnt)[i] = 0;
  __syncthreads();
  for (int t = wave; t < 64; t += 4) {
    int s = (t << 6) + lane;
    int hv = hp[s] - 1;
    unsigned long long mm = ~0ull;
#pragma unroll
    for (int bit = 0; bit < 6; ++bit) {
      unsigned long long bb = __ballot((hv >> bit) & 1);
      mm &= ((hv >> bit) & 1) ? bb : ~bb;
    }
    int rank = __popcll(mm & ((1ull << lane) - 1ull));
    hs[s] = (unsigned char)hv;
    rs[s] = (unsigned char)rank;
    if (rank == 0) tile_cnt[t][hv] = __popcll(mm);
  }
  __syncthreads();
  if (tid < 64) {
    int bkt = tid;
    int run = 0;
    for (int t = 0; t < 64; ++t) { tile_base[t][bkt] = run; run += tile_cnt[t][bkt]; }
    bucket_tot[bkt] = run;
  }
  __syncthreads();
  if (tid == 0) {
    int run = 0;
    for (int bkt = 0; bkt < 64; ++bkt) { bucket_base[bkt] = run; run += bucket_tot[bkt]; }
  }
  __syncthreads();
  for (int t = wave; t < 64; t += 4) {
    int s = (t << 6) + lane;
    int hv = hs[s];
    int pos = bucket_base[hv] + tile_base[t][hv] + rs[s];
    sorted_idx[(size_t)rb * SEQ + pos] = s;
  }
}

// ---------------------------------------------------------------------------
// Kernel 3: chunked LSH attention on MFMA (mfma_f32_16x16x32_f16).
// Per block: 64 q x 128 k window, 4 waves; wave w owns q-rows w*16..w*16+15.
// Fragments: m/n = lane&15, k = (lane>>4)*8 + j. Both operands of every mfma
// use the SAME (lane,j)->k map, so the result is invariant to the HW's actual
// k-permutation (bijection argument); C/D layout is the m89-verified mapping
// col=lane&15, row=(lane>>4)*4+reg.
// LDS (fp16): Qh[64][72] @0 (9216B), Kh[128][72] @9216 (18432B),
//             P[64][136] @0 overlays Qh/Kh after QKT (17408B),
//             Vt[64 dv][136 l] @27648 (17408B). Peak 45 KB -> 3 blocks/CU.
// Strides 72/136 halves == 4 words (mod 32): fragment b128 reads hit the even
// 8-touch/bank baseline (no m201 stride==0 pathology). Known cost: V-transpose
// u16 writes ~8-way (32 insts/thread, once) -- check SQ_LDS_BANK_CONFLICT.
// Softmax in registers on C fragments (max exact; sum reorder ~1e-7).
// fp16 staging err (4.9e-4 rel) < previous bf16-V path; threshold 0.0825.
// ---------------------------------------------------------------------------
__global__ __launch_bounds__(256) void attn_kernel(
    const float* __restrict__ q, const float* __restrict__ k,
    const float* __restrict__ v, const int* __restrict__ h,
    const int* __restrict__ sidx, float* __restrict__ out, int r,
    int accumulate) {
  int x = blockIdx.x;
  int hd = x & 7;
  int n = (x >> 3) & 63;
  int b = x >> 9;
  int rb = r * BATCH + b;

  __shared__ __align__(16) unsigned char smem[45056];
  __shared__ int orig_w[128];
  __shared__ int hw[128];
  f16* Qh = reinterpret_cast<f16*>(smem);           // [64][72]
  f16* Kh = reinterpret_cast<f16*>(smem + 9216);    // [128][72]
  const int VOFF = 27648;                           // Vt base

  int tid = threadIdx.x;
  int wave = tid >> 6;
  int lane = tid & 63;
  int lo = lane & 15;
  int hi = lane >> 4;

  if (tid < 128) {
    int j = tid;
    int sp = (j < 64) ? ((((n + 63) & 63) << 6) + j) : ((n << 6) + (j - 64));
    int orig = sidx[(size_t)rb * SEQ + sp];
    orig_w[j] = orig;
    hw[j] = h[(size_t)rb * SEQ + orig];
  }
  __syncthreads();

  const size_t gbase = (size_t)b * SEQ * DM + hd * 64;

  // ---- stage K (128x64) and Q (64x64) as fp16 ----
  float4 kreg[8], qreg[4];
#pragma unroll
  for (int t = 0; t < 8; ++t) {
    int idx = tid + t * 256;
    int j = idx >> 4, dq = idx & 15;
    kreg[t] = *reinterpret_cast<const float4*>(
        k + gbase + (size_t)orig_w[j] * DM + dq * 4);
  }
#pragma unroll
  for (int t = 0; t < 4; ++t) {
    int idx = tid + t * 256;
    int i = idx >> 4, dq = idx & 15;
    qreg[t] = *reinterpret_cast<const float4*>(
        q + gbase + (size_t)orig_w[64 + i] * DM + dq * 4);
  }
#pragma unroll
  for (int t = 0; t < 8; ++t) {
    int idx = tid + t * 256;
    int j = idx >> 4, dq = idx & 15;
    f16x4 hv = {(f16)kreg[t].x, (f16)kreg[t].y, (f16)kreg[t].z, (f16)kreg[t].w};
    *reinterpret_cast<f16x4*>(&Kh[j * 72 + dq * 4]) = hv;
  }
#pragma unroll
  for (int t = 0; t < 4; ++t) {
    int idx = tid + t * 256;
    int i = idx >> 4, dq = idx & 15;
    f16x4 hv = {(f16)qreg[t].x, (f16)qreg[t].y, (f16)qreg[t].z, (f16)qreg[t].w};
    *reinterpret_cast<f16x4*>(&Qh[i * 72 + dq * 4]) = hv;
  }
  __syncthreads();

  // issue V global loads now; they complete under QK^T (T14)
  float4 vreg[8];
#pragma unroll
  for (int t = 0; t < 8; ++t) {
    int idx = tid + t * 256;
    int l = idx >> 4, dq = idx & 15;
    vreg[t] = *reinterpret_cast<const float4*>(
        v + gbase + (size_t)orig_w[l] * DM + dq * 4);
  }

  // ---- QK^T via MFMA: wave w = q-rows w*16..+15, 8 key tiles ----
  f32x4 acc[8];
#pragma unroll
  for (int t = 0; t < 8; ++t) acc[t] = (f32x4){0.f, 0.f, 0.f, 0.f};

  int qr_a = wave * 16 + lo;  // A-fragment row
  f16x8 aq0 = *reinterpret_cast<const f16x8*>(&Qh[qr_a * 72 + hi * 8]);
  f16x8 aq1 = *reinterpret_cast<const f16x8*>(&Qh[qr_a * 72 + 32 + hi * 8]);
#pragma unroll
  for (int t = 0; t < 8; ++t) {
    f16x8 b0 = *reinterpret_cast<const f16x8*>(&Kh[(t * 16 + lo) * 72 + hi * 8]);
    f16x8 b1 = *reinterpret_cast<const f16x8*>(&Kh[(t * 16 + lo) * 72 + 32 + hi * 8]);
    acc[t] = MFMA16(aq0, b0, acc[t]);
    acc[t] = MFMA16(aq1, b1, acc[t]);
  }

  // ---- write V transposed [dv][l] fp16 (region disjoint from Qh/Kh) ----
#pragma unroll
  for (int t = 0; t < 8; ++t) {
    int idx = tid + t * 256;
    int l = idx >> 4, dq = idx & 15;
    const float* vp = &vreg[t].x;
#pragma unroll
    for (int c = 0; c < 4; ++c) {
      int dv = dq * 4 + c;
      *reinterpret_cast<f16*>(smem + VOFF + dv * 272 + l * 2) = (f16)vp[c];
    }
  }

  // ---- scale + masks + softmax in registers ----
  // lane holds C[row = wave*16 + hi*4 + rg][col = t*16 + lo]
  int hq[4];
#pragma unroll
  for (int rg = 0; rg < 4; ++rg) hq[rg] = hw[64 + wave * 16 + hi * 4 + rg];
#pragma unroll
  for (int t = 0; t < 8; ++t) {
    int key = t * 16 + lo;
    int hj = hw[key];
#pragma unroll
    for (int rg = 0; rg < 4; ++rg) {
      int qr = wave * 16 + hi * 4 + rg;
      float lg = acc[t][rg] * 0.125f;
      if (hj != hq[rg]) lg = -1e15f;  // bucket mask
      if (key == 64 + qr) lg -= 1e5f; // self mask
      acc[t][rg] = lg;
    }
  }
  float mx[4] = {-INFINITY, -INFINITY, -INFINITY, -INFINITY};
#pragma unroll
  for (int t = 0; t < 8; ++t)
#pragma unroll
    for (int rg = 0; rg < 4; ++rg) mx[rg] = fmaxf(mx[rg], acc[t][rg]);
#pragma unroll
  for (int off = 1; off <= 8; off <<= 1)
#pragma unroll
    for (int rg = 0; rg < 4; ++rg) mx[rg] = fmaxf(mx[rg], __shfl_xor(mx[rg], off));
  float sm[4] = {0.f, 0.f, 0.f, 0.f};
#pragma unroll
  for (int t = 0; t < 8; ++t)
#pragma unroll
    for (int rg = 0; rg < 4; ++rg) {
      float ev = __expf(acc[t][rg] - mx[rg]);
      acc[t][rg] = ev;
      sm[rg] += ev;
    }
#pragma unroll
  for (int off = 1; off <= 8; off <<= 1)
#pragma unroll
    for (int rg = 0; rg < 4; ++rg) sm[rg] += __shfl_xor(sm[rg], off);
  float inv[4];
#pragma unroll
  for (int rg = 0; rg < 4; ++rg) inv[rg] = 1.0f / sm[rg];

  __syncthreads();  // all Qh/Kh fragment reads complete; P may overlay

  // ---- write P fp16 [64 q][136 l] (overlay region) ----
#pragma unroll
  for (int t = 0; t < 8; ++t) {
    int key = t * 16 + lo;
#pragma unroll
    for (int rg = 0; rg < 4; ++rg) {
      int qr = wave * 16 + hi * 4 + rg;
      *reinterpret_cast<f16*>(smem + qr * 272 + key * 2) =
          (f16)(acc[t][rg] * inv[rg]);
    }
  }
  __syncthreads();

  // ---- P @ V via MFMA: wave w = q-rows w*16..+15, 4 dv tiles, K=l in 4 chunks
  f32x4 o[4];
#pragma unroll
  for (int dt = 0; dt < 4; ++dt) o[dt] = (f32x4){0.f, 0.f, 0.f, 0.f};
#pragma unroll
  for (int lt = 0; lt < 4; ++lt) {
    f16x8 ap = *reinterpret_cast<const f16x8*>(
        smem + qr_a * 272 + lt * 64 + hi * 16);
#pragma unroll
    for (int dt = 0; dt < 4; ++dt) {
      f16x8 bv = *reinterpret_cast<const f16x8*>(
          smem + VOFF + (dt * 16 + lo) * 272 + lt * 64 + hi * 16);
      o[dt] = MFMA16(ap, bv, o[dt]);
    }
  }

  // ---- output: lane holds O[row = wave*16+hi*4+rg][col = dt*16+lo] ----
#pragma unroll
  for (int dt = 0; dt < 4; ++dt) {
#pragma unroll
    for (int rg = 0; rg < 4; ++rg) {
      int qr = wave * 16 + hi * 4 + rg;
      float* dst = out + gbase + (size_t)orig_w[64 + qr] * DM + dt * 16 + lo;
      if (accumulate) {
        *dst = *dst + o[dt][rg];
      } else {
        *dst = o[dt][rg];
      }
    }
  }
}

extern "C" void kernel_launch(void* const* d_in, const int* in_sizes, int n_in,
                              void* d_out, int out_size, void* d_ws,
                              size_t ws_size, hipStream_t stream) {
  (void)out_size; (void)ws_size;
  const int R_ELEMS = ROUNDS * DM * 32;
  const float *q, *k, *v, *R;
  if (n_in >= 4 && in_sizes[0] == R_ELEMS) {  // defensive; dict order is live
    R = (const float*)d_in[0];
    k = (const float*)d_in[1];
    q = (const float*)d_in[2];
    v = (const float*)d_in[3];
  } else {
    q = (const float*)d_in[0];
    k = (const float*)d_in[1];
    v = (const float*)d_in[2];
    R = (const float*)d_in[3];
  }
  float* out = (float*)d_out;  // REFERENCE OUTPUT IS FP32
  char* ws = (char*)d_ws;
  int* h = (int*)ws;                                   // 128 KB
  int* sidx = (int*)(ws + ROUNDS * BATCH * SEQ * 4);   // 128 KB

  hash_kernel<<<ROUNDS * BATCH * (SEQ / 64), 256, 0, stream>>>(q, R, h);
  sort_kernel<<<ROUNDS * BATCH, 256, 0, stream>>>(h, sidx);
  attn_kernel<<<BATCH * NCHUNK * HEADS, 256, 0, stream>>>(q, k, v, h, sidx, out, 0, 0);
  attn_kernel<<<BATCH * NCHUNK * HEADS, 256, 0, stream>>>(q, k, v, h, sidx, out, 1, 1);
}

// Round 6
// 219.433 us; speedup vs baseline: 1.8502x; 1.0684x over previous
//
#include <hip/hip_runtime.h>
#include <hip/hip_bf16.h>
#include <hip/hip_fp16.h>

#define HEADS 8
#define DK 64
#define DV 64
#define DM 512
#define ROUNDS 2
#define SEQ 4096
#define BUCKET 64
#define NCHUNK 64
#define BATCH 4
#define GAP_THRESH 0.02f

typedef _Float16 f16;
typedef f16 f16x4 __attribute__((ext_vector_type(4)));
typedef f16 f16x8 __attribute__((ext_vector_type(8)));
typedef float f32x4 __attribute__((ext_vector_type(4)));

#define MFMA16(a, b, c) __builtin_amdgcn_mfma_f32_16x16x32_f16((a), (b), (c), 0, 0, 0)

// ---------------------------------------------------------------------------
// Kernel 1a: approximate hash via MFMA with certified error bound.
// rot[s][m] = sum_d q[s][d] R[d][m]. q,R split f16 hi+lo (q = hi+lo+eps,
// |eps|<=2^-24|q|); keep hi*hi + hi*lo + lo*hi in fp32 MFMA accum. Total
// |approx-exact| <= ~1e-4 (dropped lo*lo ~2e-5, eps terms ~4e-5, fp32 accum
// ~1.3e-5). If top2 gap > GAP_THRESH=0.02 the approx argmax == fp64 argmax
// (200x margin). Tight rows (expected ~3/32768) are flagged for exact redo.
// Fragment mappings identical to the harness-verified attn kernel:
// A/B row=lane&15, k=(lane>>4)*8+j; C row=(lane>>4)*4+reg, col=lane&15.
// R staged once in LDS (hi/lo, [m][520] f16); Q fragments read directly from
// global (rows contiguous: 16 rows x 128B per wave per kstep).
// ---------------------------------------------------------------------------
__global__ __launch_bounds__(256) void hash_approx_kernel(
    const float* __restrict__ q, const float* __restrict__ R,
    int* __restrict__ h_out, unsigned char* __restrict__ flag) {
  int blk = blockIdx.x;  // 2*4*64 = 512
  int stile = blk & 63;
  int b = (blk >> 6) & (BATCH - 1);
  int r = blk >> 8;
  int s0 = stile << 6;
  int rb = r * BATCH + b;

  __shared__ f16 Rh[32 * 520];  // 33280 B
  __shared__ f16 Rl[32 * 520];  // 33280 B

  int tid = threadIdx.x;
  int w = tid >> 6, lane = tid & 63, lo = lane & 15, hi = lane >> 4;

  // ---- stage R (512x32 fp32 -> transposed [m][d] f16 hi/lo), once ----
  const float* rbase = R + (size_t)r * DM * 32;
#pragma unroll
  for (int i = 0; i < 16; ++i) {
    int fi = tid + i * 256;
    float4 rv = *reinterpret_cast<const float4*>(rbase + fi * 4);
    int d = fi >> 3, m0 = (fi & 7) * 4;
    const float* rp = &rv.x;
#pragma unroll
    for (int e = 0; e < 4; ++e) {
      float x = rp[e];
      f16 hx = (f16)x;
      Rh[(m0 + e) * 520 + d] = hx;
      Rl[(m0 + e) * 520 + d] = (f16)(x - (float)hx);
    }
  }
  __syncthreads();

  // ---- MFMA: wave w handles q-rows w*16..+15, 2 n-tiles (m 0-15, 16-31) ----
  int qr = w * 16 + lo;
  const float* qp = q + ((size_t)b * SEQ + s0 + qr) * DM;

  f32x4 acc0 = {0.f, 0.f, 0.f, 0.f}, acc1 = {0.f, 0.f, 0.f, 0.f};
#pragma unroll 4
  for (int ks = 0; ks < 16; ++ks) {
    int k = ks * 32 + hi * 8;
    float4 a0 = *reinterpret_cast<const float4*>(qp + k);
    float4 a1 = *reinterpret_cast<const float4*>(qp + k + 4);
    float av[8] = {a0.x, a0.y, a0.z, a0.w, a1.x, a1.y, a1.z, a1.w};
    f16x8 ahi, alo;
#pragma unroll
    for (int e = 0; e < 8; ++e) {
      f16 hx = (f16)av[e];
      ahi[e] = hx;
      alo[e] = (f16)(av[e] - (float)hx);
    }
    f16x8 bh0 = *reinterpret_cast<const f16x8*>(&Rh[lo * 520 + k]);
    f16x8 bl0 = *reinterpret_cast<const f16x8*>(&Rl[lo * 520 + k]);
    f16x8 bh1 = *reinterpret_cast<const f16x8*>(&Rh[(16 + lo) * 520 + k]);
    f16x8 bl1 = *reinterpret_cast<const f16x8*>(&Rl[(16 + lo) * 520 + k]);
    acc0 = MFMA16(ahi, bh0, acc0);
    acc0 = MFMA16(ahi, bl0, acc0);
    acc0 = MFMA16(alo, bh0, acc0);
    acc1 = MFMA16(ahi, bh1, acc1);
    acc1 = MFMA16(ahi, bl1, acc1);
    acc1 = MFMA16(alo, bh1, acc1);
  }

  // ---- per-row top-2 over 64 candidates [rot, -rot], lowest-index-first ----
#pragma unroll
  for (int rg = 0; rg < 4; ++rg) {
    float c0 = acc0[rg], c1 = acc1[rg];
    float v1 = c0;
    int i1 = lo;
    float v2 = -INFINITY;
    float cv[3] = {c1, -c0, -c1};
    int ci[3] = {16 + lo, 32 + lo, 48 + lo};
#pragma unroll
    for (int c = 0; c < 3; ++c) {
      if (cv[c] > v1) { v2 = v1; v1 = cv[c]; i1 = ci[c]; }
      else v2 = fmaxf(v2, cv[c]);
    }
    // reduce across the 16 column-lanes of this row (same hi group)
#pragma unroll
    for (int off = 1; off <= 8; off <<= 1) {
      float ov1 = __shfl_xor(v1, off);
      int oi1 = __shfl_xor(i1, off);
      float ov2 = __shfl_xor(v2, off);
      if (ov1 > v1 || (ov1 == v1 && oi1 < i1)) {
        v2 = fmaxf(v1, ov2);
        v1 = ov1;
        i1 = oi1;
      } else {
        v2 = fmaxf(v2, ov1);
      }
    }
    if (lo == 0) {
      int grow = s0 + w * 16 + hi * 4 + rg;  // verified C-row mapping
      size_t gid = (size_t)rb * SEQ + grow;
      h_out[gid] = i1 + 1;
      flag[gid] = (v1 - v2 <= GAP_THRESH) ? 1 : 0;
    }
  }
}

// ---------------------------------------------------------------------------
// Kernel 1b: exact fp64 redo for flagged (tight-gap) queries. Stateless:
// scans the flag bytes (fully rewritten by 1a each launch). Expected ~3
// flagged rows total -> almost every block exits after a 64-byte check.
// fp64, deterministic ascending order -> reproduces the verified semantics.
// ---------------------------------------------------------------------------
__global__ __launch_bounds__(256) void hash_exact_kernel(
    const float* __restrict__ q, const float* __restrict__ R,
    const unsigned char* __restrict__ flag, int* __restrict__ h_out) {
  int g0 = blockIdx.x * 64;
  __shared__ int nf;
  __shared__ unsigned char list[64];
  __shared__ double pl[8][33];
  int tid = threadIdx.x;
  if (tid == 0) nf = 0;
  __syncthreads();
  if (tid < 64 && flag[g0 + tid]) {
    int idx = atomicAdd(&nf, 1);
    list[idx] = (unsigned char)tid;
  }
  __syncthreads();
  int n = nf;
  for (int i = 0; i < n; ++i) {
    int g = g0 + list[i];
    int rb = g >> 12, s = g & (SEQ - 1);
    int r = rb >> 2, b = rb & (BATCH - 1);
    int m = tid & 31, chunk = tid >> 5;
    const float* qp = q + ((size_t)b * SEQ + s) * DM;
    const float* rp = R + (size_t)r * DM * 32;
    double part = 0.0;
    for (int dd = 0; dd < 64; ++dd) {
      int d = chunk * 64 + dd;
      part = fma((double)qp[d], (double)rp[(size_t)d * 32 + m], part);
    }
    pl[chunk][m] = part;
    __syncthreads();
    if (tid < 32) {
      double sum = 0.0;
#pragma unroll
      for (int c = 0; c < 8; ++c) sum += pl[c][m];  // ascending, deterministic
      double v = sum;
      int ix = m;
      double nv = -sum;
      if (nv > v) { v = nv; ix = m + 32; }
      for (int off = 1; off <= 16; off <<= 1) {
        double ov = __shfl_xor(v, off);
        int oi = __shfl_xor(ix, off);
        if (ov > v || (ov == v && oi < ix)) { v = ov; ix = oi; }
      }
      if (tid == 0) h_out[g] = ix + 1;
    }
    __syncthreads();
  }
}

// ---------------------------------------------------------------------------
// Kernel 2: stable counting sort (ballot match-mask). UNCHANGED.
// ---------------------------------------------------------------------------
__global__ __launch_bounds__(256) void sort_kernel(const int* __restrict__ h,
                                                   int* __restrict__ sorted_idx) {
  int rb = blockIdx.x;
  const int* hp = h + (size_t)rb * SEQ;
  __shared__ unsigned char hs[SEQ];
  __shared__ unsigned char rs[SEQ];
  __shared__ int tile_cnt[64][64];
  __shared__ int tile_base[64][64];
  __shared__ int bucket_base[64];
  __shared__ int bucket_tot[64];
  int tid = threadIdx.x;
  int wave = tid >> 6, lane = tid & 63;
  for (int i = tid; i < 64 * 64; i += 256) ((int*)tile_cnt)[i] = 0;
  __syncthreads();
  for (int t = wave; t < 64; t += 4) {
    int s = (t << 6) + lane;
    int hv = hp[s] - 1;
    unsigned long long mm = ~0ull;
#pragma unroll
    for (int bit = 0; bit < 6; ++bit) {
      unsigned long long bb = __ballot((hv >> bit) & 1);
      mm &= ((hv >> bit) & 1) ? bb : ~bb;
    }
    int rank = __popcll(mm & ((1ull << lane) - 1ull));
    hs[s] = (unsigned char)hv;
    rs[s] = (unsigned char)rank;
    if (rank == 0) tile_cnt[t][hv] = __popcll(mm);
  }
  __syncthreads();
  if (tid < 64) {
    int bkt = tid;
    int run = 0;
    for (int t = 0; t < 64; ++t) { tile_base[t][bkt] = run; run += tile_cnt[t][bkt]; }
    bucket_tot[bkt] = run;
  }
  __syncthreads();
  if (tid == 0) {
    int run = 0;
    for (int bkt = 0; bkt < 64; ++bkt) { bucket_base[bkt] = run; run += bucket_tot[bkt]; }
  }
  __syncthreads();
  for (int t = wave; t < 64; t += 4) {
    int s = (t << 6) + lane;
    int hv = hs[s];
    int pos = bucket_base[hv] + tile_base[t][hv] + rs[s];
    sorted_idx[(size_t)rb * SEQ + pos] = s;
  }
}

// ---------------------------------------------------------------------------
// Kernel 3: chunked LSH attention on MFMA. UNCHANGED from verified round-4.
// ---------------------------------------------------------------------------
__global__ __launch_bounds__(256) void attn_kernel(
    const float* __restrict__ q, const float* __restrict__ k,
    const float* __restrict__ v, const int* __restrict__ h,
    const int* __restrict__ sidx, float* __restrict__ out, int r,
    int accumulate) {
  int x = blockIdx.x;
  int hd = x & 7;
  int n = (x >> 3) & 63;
  int b = x >> 9;
  int rb = r * BATCH + b;

  __shared__ __align__(16) unsigned char smem[45056];
  __shared__ int orig_w[128];
  __shared__ int hw[128];
  f16* Qh = reinterpret_cast<f16*>(smem);           // [64][72]
  f16* Kh = reinterpret_cast<f16*>(smem + 9216);    // [128][72]
  const int VOFF = 27648;                           // Vt base

  int tid = threadIdx.x;
  int wave = tid >> 6;
  int lane = tid & 63;
  int lo = lane & 15;
  int hi = lane >> 4;

  if (tid < 128) {
    int j = tid;
    int sp = (j < 64) ? ((((n + 63) & 63) << 6) + j) : ((n << 6) + (j - 64));
    int orig = sidx[(size_t)rb * SEQ + sp];
    orig_w[j] = orig;
    hw[j] = h[(size_t)rb * SEQ + orig];
  }
  __syncthreads();

  const size_t gbase = (size_t)b * SEQ * DM + hd * 64;

  // ---- stage K (128x64) and Q (64x64) as fp16 ----
  float4 kreg[8], qreg[4];
#pragma unroll
  for (int t = 0; t < 8; ++t) {
    int idx = tid + t * 256;
    int j = idx >> 4, dq = idx & 15;
    kreg[t] = *reinterpret_cast<const float4*>(
        k + gbase + (size_t)orig_w[j] * DM + dq * 4);
  }
#pragma unroll
  for (int t = 0; t < 4; ++t) {
    int idx = tid + t * 256;
    int i = idx >> 4, dq = idx & 15;
    qreg[t] = *reinterpret_cast<const float4*>(
        q + gbase + (size_t)orig_w[64 + i] * DM + dq * 4);
  }
#pragma unroll
  for (int t = 0; t < 8; ++t) {
    int idx = tid + t * 256;
    int j = idx >> 4, dq = idx & 15;
    f16x4 hv = {(f16)kreg[t].x, (f16)kreg[t].y, (f16)kreg[t].z, (f16)kreg[t].w};
    *reinterpret_cast<f16x4*>(&Kh[j * 72 + dq * 4]) = hv;
  }
#pragma unroll
  for (int t = 0; t < 4; ++t) {
    int idx = tid + t * 256;
    int i = idx >> 4, dq = idx & 15;
    f16x4 hv = {(f16)qreg[t].x, (f16)qreg[t].y, (f16)qreg[t].z, (f16)qreg[t].w};
    *reinterpret_cast<f16x4*>(&Qh[i * 72 + dq * 4]) = hv;
  }
  __syncthreads();

  // issue V global loads now; they complete under QK^T (T14)
  float4 vreg[8];
#pragma unroll
  for (int t = 0; t < 8; ++t) {
    int idx = tid + t * 256;
    int l = idx >> 4, dq = idx & 15;
    vreg[t] = *reinterpret_cast<const float4*>(
        v + gbase + (size_t)orig_w[l] * DM + dq * 4);
  }

  // ---- QK^T via MFMA ----
  f32x4 acc[8];
#pragma unroll
  for (int t = 0; t < 8; ++t) acc[t] = (f32x4){0.f, 0.f, 0.f, 0.f};

  int qr_a = wave * 16 + lo;
  f16x8 aq0 = *reinterpret_cast<const f16x8*>(&Qh[qr_a * 72 + hi * 8]);
  f16x8 aq1 = *reinterpret_cast<const f16x8*>(&Qh[qr_a * 72 + 32 + hi * 8]);
#pragma unroll
  for (int t = 0; t < 8; ++t) {
    f16x8 b0 = *reinterpret_cast<const f16x8*>(&Kh[(t * 16 + lo) * 72 + hi * 8]);
    f16x8 b1 = *reinterpret_cast<const f16x8*>(&Kh[(t * 16 + lo) * 72 + 32 + hi * 8]);
    acc[t] = MFMA16(aq0, b0, acc[t]);
    acc[t] = MFMA16(aq1, b1, acc[t]);
  }

  // ---- write V transposed [dv][l] fp16 ----
#pragma unroll
  for (int t = 0; t < 8; ++t) {
    int idx = tid + t * 256;
    int l = idx >> 4, dq = idx & 15;
    const float* vp = &vreg[t].x;
#pragma unroll
    for (int c = 0; c < 4; ++c) {
      int dv = dq * 4 + c;
      *reinterpret_cast<f16*>(smem + VOFF + dv * 272 + l * 2) = (f16)vp[c];
    }
  }

  // ---- scale + masks + softmax in registers ----
  int hq[4];
#pragma unroll
  for (int rg = 0; rg < 4; ++rg) hq[rg] = hw[64 + wave * 16 + hi * 4 + rg];
#pragma unroll
  for (int t = 0; t < 8; ++t) {
    int key = t * 16 + lo;
    int hj = hw[key];
#pragma unroll
    for (int rg = 0; rg < 4; ++rg) {
      int qr = wave * 16 + hi * 4 + rg;
      float lg = acc[t][rg] * 0.125f;
      if (hj != hq[rg]) lg = -1e15f;
      if (key == 64 + qr) lg -= 1e5f;
      acc[t][rg] = lg;
    }
  }
  float mx[4] = {-INFINITY, -INFINITY, -INFINITY, -INFINITY};
#pragma unroll
  for (int t = 0; t < 8; ++t)
#pragma unroll
    for (int rg = 0; rg < 4; ++rg) mx[rg] = fmaxf(mx[rg], acc[t][rg]);
#pragma unroll
  for (int off = 1; off <= 8; off <<= 1)
#pragma unroll
    for (int rg = 0; rg < 4; ++rg) mx[rg] = fmaxf(mx[rg], __shfl_xor(mx[rg], off));
  float sm[4] = {0.f, 0.f, 0.f, 0.f};
#pragma unroll
  for (int t = 0; t < 8; ++t)
#pragma unroll
    for (int rg = 0; rg < 4; ++rg) {
      float ev = __expf(acc[t][rg] - mx[rg]);
      acc[t][rg] = ev;
      sm[rg] += ev;
    }
#pragma unroll
  for (int off = 1; off <= 8; off <<= 1)
#pragma unroll
    for (int rg = 0; rg < 4; ++rg) sm[rg] += __shfl_xor(sm[rg], off);
  float inv[4];
#pragma unroll
  for (int rg = 0; rg < 4; ++rg) inv[rg] = 1.0f / sm[rg];

  __syncthreads();

  // ---- write P fp16 [64 q][136 l] ----
#pragma unroll
  for (int t = 0; t < 8; ++t) {
    int key = t * 16 + lo;
#pragma unroll
    for (int rg = 0; rg < 4; ++rg) {
      int qr = wave * 16 + hi * 4 + rg;
      *reinterpret_cast<f16*>(smem + qr * 272 + key * 2) =
          (f16)(acc[t][rg] * inv[rg]);
    }
  }
  __syncthreads();

  // ---- P @ V via MFMA ----
  f32x4 o[4];
#pragma unroll
  for (int dt = 0; dt < 4; ++dt) o[dt] = (f32x4){0.f, 0.f, 0.f, 0.f};
#pragma unroll
  for (int lt = 0; lt < 4; ++lt) {
    f16x8 ap = *reinterpret_cast<const f16x8*>(
        smem + qr_a * 272 + lt * 64 + hi * 16);
#pragma unroll
    for (int dt = 0; dt < 4; ++dt) {
      f16x8 bv = *reinterpret_cast<const f16x8*>(
          smem + VOFF + (dt * 16 + lo) * 272 + lt * 64 + hi * 16);
      o[dt] = MFMA16(ap, bv, o[dt]);
    }
  }

  // ---- output ----
#pragma unroll
  for (int dt = 0; dt < 4; ++dt) {
#pragma unroll
    for (int rg = 0; rg < 4; ++rg) {
      int qr = wave * 16 + hi * 4 + rg;
      float* dst = out + gbase + (size_t)orig_w[64 + qr] * DM + dt * 16 + lo;
      if (accumulate) {
        *dst = *dst + o[dt][rg];
      } else {
        *dst = o[dt][rg];
      }
    }
  }
}

extern "C" void kernel_launch(void* const* d_in, const int* in_sizes, int n_in,
                              void* d_out, int out_size, void* d_ws,
                              size_t ws_size, hipStream_t stream) {
  (void)out_size; (void)ws_size;
  const int R_ELEMS = ROUNDS * DM * 32;
  const float *q, *k, *v, *R;
  if (n_in >= 4 && in_sizes[0] == R_ELEMS) {  // defensive; dict order is live
    R = (const float*)d_in[0];
    k = (const float*)d_in[1];
    q = (const float*)d_in[2];
    v = (const float*)d_in[3];
  } else {
    q = (const float*)d_in[0];
    k = (const float*)d_in[1];
    v = (const float*)d_in[2];
    R = (const float*)d_in[3];
  }
  float* out = (float*)d_out;  // REFERENCE OUTPUT IS FP32
  char* ws = (char*)d_ws;
  int* h = (int*)ws;                                          // 128 KB
  int* sidx = (int*)(ws + ROUNDS * BATCH * SEQ * 4);          // 128 KB
  unsigned char* flag = (unsigned char*)(ws + 2 * ROUNDS * BATCH * SEQ * 4);  // 32 KB

  hash_approx_kernel<<<ROUNDS * BATCH * (SEQ / 64), 256, 0, stream>>>(q, R, h, flag);
  hash_exact_kernel<<<ROUNDS * BATCH * (SEQ / 64), 256, 0, stream>>>(q, R, flag, h);
  sort_kernel<<<ROUNDS * BATCH, 256, 0, stream>>>(h, sidx);
  attn_kernel<<<BATCH * NCHUNK * HEADS, 256, 0, stream>>>(q, k, v, h, sidx, out, 0, 0);
  attn_kernel<<<BATCH * NCHUNK * HEADS, 256, 0, stream>>>(q, k, v, h, sidx, out, 1, 1);
}